// Round 11
// baseline (479.868 us; speedup 1.0000x reference)
//
#include <hip/hip_runtime.h>
#include <math.h>

#define NN 100000
#define EIN 800000
#define EEX 400000
#define ND 35
#define H 128
#define NG 256
#define NL 4
#define TM 16          // nodes per tile (MFMA M)
#define TML 16         // nodes per block in lin_node
#define NTILES 6250    // NN/TM
#define CAPI 32        // bucket capacity intra (deg ~ Poisson(8))
#define CAPE 16        // bucket capacity inter (deg ~ Poisson(4))
#define OVFCAP 16384   // overflow list capacity
#define EPT 4          // edges per thread in fill (ILP x TLP balance)

typedef unsigned short u16;
typedef unsigned char u8;
typedef short s8v __attribute__((ext_vector_type(8)));   // 8 bf16 (4 VGPRs)
typedef float f4v __attribute__((ext_vector_type(4)));   // 4 fp32 acc
typedef float f2v __attribute__((ext_vector_type(2)));

__device__ __forceinline__ float silu_f(float x){ return x / (1.0f + __expf(-x)); }
__device__ __forceinline__ float bf2f(u16 v){ return __uint_as_float(((unsigned)v) << 16); }
__device__ __forceinline__ float bfw_lo(unsigned u){ return __uint_as_float(u << 16); }
__device__ __forceinline__ float bfw_hi(unsigned u){ return __uint_as_float(u & 0xffff0000u); }
__device__ __forceinline__ u16 f2bf(float f){
  unsigned u = __float_as_uint(f);
  u += 0x7FFFu + ((u >> 16) & 1u);   // RNE
  return (u16)(u >> 16);
}
__device__ __forceinline__ u8 f2fp8(float f){
  int p = __builtin_amdgcn_cvt_pk_fp8_f32(f, f, 0, false);   // OCP e4m3 on gfx950
  return (u8)(p & 0xff);
}
// pack two f32 -> one dword of two bf16 (RNE), same layout as manual f2bf pair
__device__ __forceinline__ unsigned pk_bf16(float lo, float hi){
  unsigned r;
  asm("v_cvt_pk_bf16_f32 %0, %1, %2" : "=v"(r) : "v"(lo), "v"(hi));
  return r;
}
// pack (src:17, bf16(w):15) -> 4B.  w > 0 so its sign bit is 0 and bf16 fits 15 bits.
__device__ __forceinline__ unsigned pack_ew(int s, float w){
  return ((unsigned)s << 15) | (unsigned)f2bf(w);
}

// ---------------- merged prep: wfrag (blocks 0..7) + MFMA lin_node + batched bucket fill ----------------
__global__ __launch_bounds__(256) void k_prep(const float* __restrict__ x,
                                              const float* __restrict__ lnW,
                                              const float* __restrict__ lnb,
                                              u16* __restrict__ h,
                                              u8* __restrict__ h8,
                                              const float* __restrict__ WI,
                                              const float* __restrict__ WE,
                                              u16* __restrict__ WfI,
                                              u16* __restrict__ WfE,
                                              const int* __restrict__ src_i,
                                              const int* __restrict__ dst_i,
                                              const float* __restrict__ ea,
                                              const int* __restrict__ src_e,
                                              const int* __restrict__ dst_e,
                                              const float* __restrict__ pos,
                                              int* __restrict__ cnt_i,
                                              int* __restrict__ cnt_e,
                                              unsigned* __restrict__ bktI,
                                              unsigned* __restrict__ bktE,
                                              int* __restrict__ ovfhdr,
                                              int4* __restrict__ ovfList){
  const int NBW = 2*NL;          // 8 weight-swizzle blocks
  const int NBL = NN/TML;        // 6250 lin_node blocks
  if (blockIdx.x < NBW){
    const int lm = blockIdx.x;
    const int l = lm >> 1;
    const float* src = (lm & 1) ? (WE + (size_t)l*H*H) : (WI + (size_t)l*H*H);
    u16* dst = ((lm & 1) ? WfE : WfI) + (size_t)l*H*H;
    for (int idx = threadIdx.x; idx < H*H; idx += 256){
      const int r = idx & 7, lane = (idx>>3)&63, kc = (idx>>9)&3, jt = idx>>11;
      const int k = kc*32 + (lane>>4)*8 + r;
      const int j = jt*16 + (lane&15);
      dst[idx] = f2bf(src[k*H + j]);
    }
    return;
  }
  if (blockIdx.x < NBW + NBL){
    // ---- MFMA lin_node: h = silu(x @ lnW + lnb), 16 nodes/block ----
    __shared__ u16 xs[TM][72];   // row pad 72: 2-way bank alias only (free, m136)
    const int n0 = (blockIdx.x - NBW) * TML;
    const int tid = threadIdx.x;
    for (int i = tid; i < TM*64; i += 256){
      const int m = i >> 6, k = i & 63;
      xs[m][k] = (k < ND) ? f2bf(x[(size_t)(n0+m)*ND + k]) : (u16)0;
    }
    __syncthreads();
    const int lane = tid & 63;
    const int wv   = tid >> 6;
    const int col  = lane & 15;
    const int quad = lane >> 4;
    const int jta = 2*wv, jtb = 2*wv + 1;
    const int ja = jta*16 + col, jb = jtb*16 + col;

    f4v accA = {0.f,0.f,0.f,0.f}, accB = {0.f,0.f,0.f,0.f};
    #pragma unroll
    for (int kc = 0; kc < 2; ++kc){
      const s8v a = *(const s8v*)&xs[col][kc*32 + quad*8];
      s8v bA, bB;
      #pragma unroll
      for (int r = 0; r < 8; ++r){
        const int k = kc*32 + quad*8 + r;
        bA[r] = (k < ND) ? (short)f2bf(lnW[k*H + ja]) : (short)0;
        bB[r] = (k < ND) ? (short)f2bf(lnW[k*H + jb]) : (short)0;
      }
      accA = __builtin_amdgcn_mfma_f32_16x16x32_bf16(a, bA, accA, 0, 0, 0);
      accB = __builtin_amdgcn_mfma_f32_16x16x32_bf16(a, bB, accB, 0, 0, 0);
    }
    const float bja = lnb[ja], bjb = lnb[jb];
    #pragma unroll
    for (int r = 0; r < 4; ++r){
      const int n = n0 + quad*4 + r;           // C/D: col=lane&15, row=quad*4+reg (m89)
      const float ha = silu_f(accA[r] + bja);
      const float hb = silu_f(accB[r] + bjb);
      h[(size_t)n*H + ja] = f2bf(ha);
      h[(size_t)n*H + jb] = f2bf(hb);
      h8[(size_t)n*H + ja] = f2fp8(ha);
      h8[(size_t)n*H + jb] = f2fp8(hb);
    }
    return;
  }
  // ---- batched bucket fill: issue atomics EARLY, hide their latency under the
  // w-computation (pos gathers + exp), then store.  EPT chains in flight. ----
  const int NE_ALL_ = EIN + EEX;
  const int base = (blockIdx.x - NBW - NBL)*(256*EPT) + (int)threadIdx.x;
  int eV[EPT], sV[EPT], dV[EPT];
  #pragma unroll
  for (int k = 0; k < EPT; ++k){
    const int e = base + k*256;
    eV[k] = e;
    int s = 0, d = 0;
    if (e < EIN){ s = src_i[e]; d = dst_i[e]; }
    else if (e < NE_ALL_){ s = src_e[e-EIN]; d = dst_e[e-EIN]; }
    sV[k] = s; dV[k] = d;
  }
  // issue all slot atomics NOW (independent of w)
  int slotV[EPT];
  #pragma unroll
  for (int k = 0; k < EPT; ++k){
    const int e = eV[k];
    if (e < EIN)           slotV[k] = atomicAdd(&cnt_i[dV[k]], 1);
    else if (e < NE_ALL_)  slotV[k] = atomicAdd(&cnt_e[dV[k]], 1);
    else                   slotV[k] = 0;
  }
  // compute w while atomics are in flight
  float wV[EPT];
  #pragma unroll
  for (int k = 0; k < EPT; ++k){
    const int e = eV[k];
    float w = 0.f;
    if (e < EIN) w = ea[e];
    else if (e < NE_ALL_){
      const int s = sV[k], d = dV[k];
      const float dx = pos[3*s+0] - pos[3*d+0];
      const float dy = pos[3*s+1] - pos[3*d+1];
      const float dz = pos[3*s+2] - pos[3*d+2];
      w = __expf(-(dx*dx + dy*dy + dz*dz));
    }
    wV[k] = w;
  }
  // stores
  #pragma unroll
  for (int k = 0; k < EPT; ++k){
    const int e = eV[k];
    if (e < EIN){
      const int slot = slotV[k];
      if (slot < CAPI) bktI[((size_t)dV[k] << 5) + slot] = pack_ew(sV[k], wV[k]);
      else {
        const int oi = atomicAdd(ovfhdr, 1);
        if (oi < OVFCAP) ovfList[oi] = make_int4(dV[k], sV[k], __float_as_int(wV[k]), 0);
      }
    } else if (e < NE_ALL_){
      const int slot = slotV[k];
      if (slot < CAPE) bktE[((size_t)dV[k] << 4) + slot] = pack_ew(sV[k], wV[k]);
      else {
        const int oi = atomicAdd(ovfhdr, 1);
        if (oi < OVFCAP) ovfList[oi] = make_int4(dV[k], sV[k], __float_as_int(wV[k]), 1);
      }
    }
  }
}

// accumulate one fp8x8 row-chunk (two dwords) scaled by vv into 4 f2v accumulators
#define ACCONE(qx, qy, vv, A0, A1, A2, A3) {                                          \
    const f2v x01 = __builtin_amdgcn_cvt_pk_f32_fp8((int)(qx), false);                \
    const f2v x23 = __builtin_amdgcn_cvt_pk_f32_fp8((int)(qx), true);                 \
    const f2v x45 = __builtin_amdgcn_cvt_pk_f32_fp8((int)(qy), false);                \
    const f2v x67 = __builtin_amdgcn_cvt_pk_f32_fp8((int)(qy), true);                 \
    A0 += x01 * (vv); A1 += x23 * (vv); A2 += x45 * (vv); A3 += x67 * (vv); }

// ---------------- shared memory: 8.7KB, time-shared between phases ----------------
#define GATHER_SHARED_DECL                                                            \
  __shared__ __align__(16) char smem_[8704];                                          \
  u16 (*aggIs)[136] = (u16(*)[136])(smem_);                                           \
  u16 (*aggEs)[136] = (u16(*)[136])(smem_ + 4352);                                    \
  u16 (*mifh)[136] = (u16(*)[136])(smem_);                                            \
  u16 (*mefh)[136] = (u16(*)[136])(smem_ + 4352);                                     \
  float (*pf)[132] = (float(*)[132])(smem_);

// per-thread identity + degrees + output index (live through the whole kernel)
#define GATHER_DECLS                                                                  \
  const int slot = tid >> 4;                                                          \
  const int l16  = tid & 15;                                                          \
  const int j8 = l16 * 8;                                                             \
  const int n = n0 + slot;                                                            \
  const int cIv = cntI[n];                                                            \
  const int cEv = cntE[n];                                                            \
  const unsigned idx8 = (unsigned)n*H + (unsigned)j8;

// 8-deep intra + 4-deep inter batches; edge words read direct from global rows
// (uint4, wave-broadcast).  Pad entries (src=0,w=0) contribute exactly 0.0.
#define GATHER_LDS_BODY                                                               \
  {                                                                                   \
    const int uI = cIv < CAPI ? cIv : CAPI;                                           \
    const int uE = cEv < CAPE ? cEv : CAPE;                                           \
    const int pIv = (uI + 7) & ~7;                                                    \
    const int pEv = (uE + 3) & ~3;                                                    \
    const unsigned* rowIp = bktI + ((size_t)n << 5);                                  \
    const unsigned* rowEp = bktE + ((size_t)n << 4);                                  \
    f2v aI0={0.f,0.f}, aI1={0.f,0.f}, aI2={0.f,0.f}, aI3={0.f,0.f};                   \
    f2v aE0={0.f,0.f}, aE1={0.f,0.f}, aE2={0.f,0.f}, aE3={0.f,0.f};                   \
    {                                                                                 \
      const int nbI_ = pIv >> 3, nbE_ = pEv >> 2;                                     \
      const int nb = nbI_ > nbE_ ? nbI_ : nbE_;                                       \
      int tIi = 0, tEi = 0;                                                           \
      for (int b = 0; b < nb; ++b){                                                   \
        const bool doI = b < nbI_;                                                    \
        const bool doE = b < nbE_;                                                    \
        unsigned eIw[8], eEw[4]; uint2 qI[8], qE[4];                                  \
        if (doI){                                                                     \
          *(uint4*)&eIw[0] = *(const uint4*)(rowIp + tIi);                            \
          *(uint4*)&eIw[4] = *(const uint4*)(rowIp + tIi + 4);                        \
          _Pragma("unroll")                                                           \
          for (int k = 0; k < 8; ++k){                                                \
            const unsigned off = ((eIw[k] >> 15) << 7) | (unsigned)j8;                \
            qI[k] = *(const uint2*)(hin8 + off);                                      \
          }                                                                           \
        }                                                                             \
        if (doE){                                                                     \
          *(uint4*)&eEw[0] = *(const uint4*)(rowEp + tEi);                            \
          _Pragma("unroll")                                                           \
          for (int k = 0; k < 4; ++k){                                                \
            const unsigned off = ((eEw[k] >> 15) << 7) | (unsigned)j8;                \
            qE[k] = *(const uint2*)(hin8 + off);                                      \
          }                                                                           \
        }                                                                             \
        if (doI){                                                                     \
          _Pragma("unroll")                                                           \
          for (int k = 0; k < 8; ++k){                                                \
            const float v = __uint_as_float((eIw[k] & 0x7fffu) << 16);                \
            ACCONE(qI[k].x, qI[k].y, v, aI0, aI1, aI2, aI3)                           \
          }                                                                           \
          tIi += 8;                                                                   \
        }                                                                             \
        if (doE){                                                                     \
          _Pragma("unroll")                                                           \
          for (int k = 0; k < 4; ++k){                                                \
            const float v = __uint_as_float((eEw[k] & 0x7fffu) << 16);                \
            ACCONE(qE[k].x, qE[k].y, v, aE0, aE1, aE2, aE3)                           \
          }                                                                           \
          tEi += 4;                                                                   \
        }                                                                             \
      }                                                                               \
    }                                                                                 \
    const int nov = ovfhdr[0];                                                        \
    if (__builtin_expect(nov > 0, 0)){                                                \
      const int novc = nov < OVFCAP ? nov : OVFCAP;                                   \
      for (int o = 0; o < novc; ++o){                                                 \
        const int4 E = ovfList[o];                                                    \
        if (E.x == n){                                                                \
          const unsigned off = ((unsigned)E.y << 7) | (unsigned)j8;                   \
          const uint2 q = *(const uint2*)(hin8 + off);                                \
          const float v = __int_as_float(E.z);                                        \
          if (E.w == 0){ ACCONE(q.x, q.y, v, aI0, aI1, aI2, aI3) }                    \
          else         { ACCONE(q.x, q.y, v, aE0, aE1, aE2, aE3) }                    \
        }                                                                             \
      }                                                                               \
    }                                                                                 \
    *(uint4*)&aggIs[slot][j8] = make_uint4(pk_bf16(aI0.x, aI0.y), pk_bf16(aI1.x, aI1.y), \
                                           pk_bf16(aI2.x, aI2.y), pk_bf16(aI3.x, aI3.y)); \
    *(uint4*)&aggEs[slot][j8] = make_uint4(pk_bf16(aE0.x, aE0.y), pk_bf16(aE1.x, aE1.y), \
                                           pk_bf16(aE2.x, aE2.y), pk_bf16(aE3.x, aE3.y)); \
  }

#define MFMA_BODY                                                                     \
  f4v accIA = {0.f,0.f,0.f,0.f}, accIB = {0.f,0.f,0.f,0.f};                           \
  f4v accEA = {0.f,0.f,0.f,0.f}, accEB = {0.f,0.f,0.f,0.f};                           \
  _Pragma("unroll")                                                                   \
  for (int kc = 0; kc < 4; ++kc){                                                     \
    const int koff = kc*32 + quad*8;                                                  \
    const s8v aI = *(const s8v*)&aggIs[col][koff];                                    \
    const s8v aE = *(const s8v*)&aggEs[col][koff];                                    \
    const s8v bIA = *(const s8v*)(WfI + (((jta*4 + kc)*64 + lane) << 3));             \
    const s8v bIB = *(const s8v*)(WfI + (((jtb*4 + kc)*64 + lane) << 3));             \
    const s8v bEA = *(const s8v*)(WfE + (((jta*4 + kc)*64 + lane) << 3));             \
    const s8v bEB = *(const s8v*)(WfE + (((jtb*4 + kc)*64 + lane) << 3));             \
    accIA = __builtin_amdgcn_mfma_f32_16x16x32_bf16(aI, bIA, accIA, 0, 0, 0);         \
    accIB = __builtin_amdgcn_mfma_f32_16x16x32_bf16(aI, bIB, accIB, 0, 0, 0);         \
    accEA = __builtin_amdgcn_mfma_f32_16x16x32_bf16(aE, bEA, accEA, 0, 0, 0);         \
    accEB = __builtin_amdgcn_mfma_f32_16x16x32_bf16(aE, bEB, accEB, 0, 0, 0);         \
  }

// transpose acc (C-layout, scattered) -> LDS [node][col] bf16.
#define ACC2LDS                                                                       \
  __syncthreads();                                                                    \
  _Pragma("unroll")                                                                   \
  for (int r = 0; r < 4; ++r){                                                        \
    mifh[quad*4+r][jta*16+col] = f2bf(accIA[r]);                                      \
    mifh[quad*4+r][jtb*16+col] = f2bf(accIB[r]);                                      \
    mefh[quad*4+r][jta*16+col] = f2bf(accEA[r]);                                      \
    mefh[quad*4+r][jtb*16+col] = f2bf(accEB[r]);                                      \
  }                                                                                   \
  __syncthreads();

#define EPI_COMMON                                                                    \
  const float cIf = (float)cIv;                                                       \
  const float cEf = (float)cEv;                                                       \
  const float rdI = 1.0f / (cIf + 1.0f);                                              \
  const float ldE = __logf(cEf + 1.0f);                                               \
  const uint4 miq = *(const uint4*)&mifh[slot][j8];                                   \
  const uint4 meq = *(const uint4*)&mefh[slot][j8];                                   \
  const unsigned miw[4] = {miq.x, miq.y, miq.z, miq.w};                               \
  const unsigned mew[4] = {meq.x, meq.y, meq.z, meq.w};                               \
  const f4v bIa_ = *(const f4v*)(bI + j8);                                            \
  const f4v bIb_ = *(const f4v*)(bI + j8 + 4);                                        \
  const f4v bEa_ = *(const f4v*)(bE + j8);                                            \
  const f4v bEb_ = *(const f4v*)(bE + j8 + 4);

#define MI_AT(k) ((k & 1) ? bfw_hi(miw[k>>1]) : bfw_lo(miw[k>>1]))
#define ME_AT(k) ((k & 1) ? bfw_hi(mew[k>>1]) : bfw_lo(mew[k>>1]))

#define STORE_STATE8                                                                  \
  uint4 vps, vls, hs;                                                                 \
  vps.x = pk_bf16(vpn[0],vpn[1]); vps.y = pk_bf16(vpn[2],vpn[3]);                     \
  vps.z = pk_bf16(vpn[4],vpn[5]); vps.w = pk_bf16(vpn[6],vpn[7]);                     \
  vls.x = pk_bf16(vln[0],vln[1]); vls.y = pk_bf16(vln[2],vln[3]);                     \
  vls.z = pk_bf16(vln[4],vln[5]); vls.w = pk_bf16(vln[6],vln[7]);                     \
  hs.x = pk_bf16(hnew[0],hnew[1]); hs.y = pk_bf16(hnew[2],hnew[3]);                   \
  hs.z = pk_bf16(hnew[4],hnew[5]); hs.w = pk_bf16(hnew[6],hnew[7]);                   \
  *(uint4*)(vp + idx8) = vps;                                                         \
  *(uint4*)(vl + idx8) = vls;                                                         \
  *(uint4*)(hout + idx8) = hs;                                                        \
  int d0_ = __builtin_amdgcn_cvt_pk_fp8_f32(hnew[0], hnew[1], 0, false);              \
  d0_ = __builtin_amdgcn_cvt_pk_fp8_f32(hnew[2], hnew[3], d0_, true);                 \
  int d1_ = __builtin_amdgcn_cvt_pk_fp8_f32(hnew[4], hnew[5], 0, false);              \
  d1_ = __builtin_amdgcn_cvt_pk_fp8_f32(hnew[6], hnew[7], d1_, true);                 \
  uint2 h8s; h8s.x = (unsigned)d0_; h8s.y = (unsigned)d1_;                            \
  *(uint2*)(hout8 + idx8) = h8s;

// ---------------- layers 1..2: read state, write hout + fp8 mirror ----------------
__global__ __launch_bounds__(256, 4) void k_layer(
    const u16* __restrict__ hin, const u8* __restrict__ hin8,
    u16* __restrict__ hout, u8* __restrict__ hout8,
    u16* __restrict__ vp, u16* __restrict__ vl,
    const int* __restrict__ cntI, const int* __restrict__ cntE,
    const unsigned* __restrict__ bktI, const unsigned* __restrict__ bktE,
    const int* __restrict__ ovfhdr, const int4* __restrict__ ovfList,
    const u16* __restrict__ WfI, const float* __restrict__ bI,
    const u16* __restrict__ WfE, const float* __restrict__ bE)
{
  GATHER_SHARED_DECL
  const int n0 = blockIdx.x * TM;
  const int tid = threadIdx.x;
  GATHER_DECLS
  // T14: issue epilogue state loads EARLY -- latency hides under the gather phase
  const uint4 vpq = *(const uint4*)(vp + idx8);
  const uint4 vlq = *(const uint4*)(vl + idx8);
  const uint4 hq  = *(const uint4*)(hin + idx8);
  GATHER_LDS_BODY
  __syncthreads();

  const int lane = tid & 63;
  const int w    = tid >> 6;
  const int jta = 2*w, jtb = 2*w + 1;
  const int col  = lane & 15;
  const int quad = lane >> 4;
  MFMA_BODY
  ACC2LDS

  EPI_COMMON
  const unsigned vpw[4] = {vpq.x, vpq.y, vpq.z, vpq.w};
  const unsigned vlw[4] = {vlq.x, vlq.y, vlq.z, vlq.w};
  const unsigned hwv[4] = {hq.x, hq.y, hq.z, hq.w};
  float vpn[8], vln[8], hnew[8];
  #pragma unroll
  for (int k = 0; k < 8; ++k){
    const float bIv = (k < 4) ? bIa_[k] : bIb_[k-4];
    const float bEv = (k < 4) ? bEa_[k] : bEb_[k-4];
    const float mi = (MI_AT(k) + cIf*bIv) * rdI;
    const float me = (ME_AT(k) + cEf*bEv) * ldE;
    const float vpo = (k & 1) ? bfw_hi(vpw[k>>1]) : bfw_lo(vpw[k>>1]);
    const float vlo = (k & 1) ? bfw_hi(vlw[k>>1]) : bfw_lo(vlw[k>>1]);
    const float ho  = (k & 1) ? bfw_hi(hwv[k>>1]) : bfw_lo(hwv[k>>1]);
    vpn[k] = silu_f(mi + vpo);
    vln[k] = silu_f(me + vlo);
    hnew[k] = ho + vpn[k] + vln[k];
  }
  STORE_STATE8
}

// ---------------- layer 0: vp/vl start at zero (no reads) ----------------
__global__ __launch_bounds__(256, 4) void k_layer0(
    const u16* __restrict__ hin, const u8* __restrict__ hin8,
    u16* __restrict__ hout, u8* __restrict__ hout8,
    u16* __restrict__ vp, u16* __restrict__ vl,
    const int* __restrict__ cntI, const int* __restrict__ cntE,
    const unsigned* __restrict__ bktI, const unsigned* __restrict__ bktE,
    const int* __restrict__ ovfhdr, const int4* __restrict__ ovfList,
    const u16* __restrict__ WfI, const float* __restrict__ bI,
    const u16* __restrict__ WfE, const float* __restrict__ bE)
{
  GATHER_SHARED_DECL
  const int n0 = blockIdx.x * TM;
  const int tid = threadIdx.x;
  GATHER_DECLS
  const uint4 hq = *(const uint4*)(hin + idx8);   // T14 early issue
  GATHER_LDS_BODY
  __syncthreads();

  const int lane = tid & 63;
  const int w    = tid >> 6;
  const int jta = 2*w, jtb = 2*w + 1;
  const int col  = lane & 15;
  const int quad = lane >> 4;
  MFMA_BODY
  ACC2LDS

  EPI_COMMON
  const unsigned hwv[4] = {hq.x, hq.y, hq.z, hq.w};
  float vpn[8], vln[8], hnew[8];
  #pragma unroll
  for (int k = 0; k < 8; ++k){
    const float bIv = (k < 4) ? bIa_[k] : bIb_[k-4];
    const float bEv = (k < 4) ? bEa_[k] : bEb_[k-4];
    const float mi = (MI_AT(k) + cIf*bIv) * rdI;
    const float me = (ME_AT(k) + cEf*bEv) * ldE;
    const float ho = (k & 1) ? bfw_hi(hwv[k>>1]) : bfw_lo(hwv[k>>1]);
    vpn[k] = silu_f(mi);
    vln[k] = silu_f(me);
    hnew[k] = ho + vpn[k] + vln[k];
  }
  STORE_STATE8
}

// ---------------- layer 3: NO state stores; pool fused from registers ----------------
__global__ __launch_bounds__(256, 4) void k_layer3(
    const u16* __restrict__ hin, const u8* __restrict__ hin8,
    u16* __restrict__ vp, u16* __restrict__ vl,
    const int* __restrict__ cntI, const int* __restrict__ cntE,
    const unsigned* __restrict__ bktI, const unsigned* __restrict__ bktE,
    const int* __restrict__ ovfhdr, const int4* __restrict__ ovfList,
    const u16* __restrict__ WfI, const float* __restrict__ bI,
    const u16* __restrict__ WfE, const float* __restrict__ bE,
    const int* __restrict__ batch, float* __restrict__ gp)
{
  GATHER_SHARED_DECL
  const int n0 = blockIdx.x * TM;
  const int tid = threadIdx.x;
  GATHER_DECLS
  // T14 early issue: state loads + batch ids
  const uint4 vpq = *(const uint4*)(vp + idx8);
  const uint4 vlq = *(const uint4*)(vl + idx8);
  const uint4 hq  = *(const uint4*)(hin + idx8);
  const int b0 = batch[n0];
  const int b15 = batch[n0 + TM - 1];
  const int bn = batch[n];
  GATHER_LDS_BODY
  __syncthreads();

  const int lane = tid & 63;
  const int w    = tid >> 6;
  const int jta = 2*w, jtb = 2*w + 1;
  const int col  = lane & 15;
  const int quad = lane >> 4;
  MFMA_BODY
  ACC2LDS

  EPI_COMMON
  const unsigned vpw[4] = {vpq.x, vpq.y, vpq.z, vpq.w};
  const unsigned vlw[4] = {vlq.x, vlq.y, vlq.z, vlq.w};
  const unsigned hwv[4] = {hq.x, hq.y, hq.z, hq.w};
  float hnew[8];
  #pragma unroll
  for (int k = 0; k < 8; ++k){
    const float bIv = (k < 4) ? bIa_[k] : bIb_[k-4];
    const float bEv = (k < 4) ? bEa_[k] : bEb_[k-4];
    const float mi = (MI_AT(k) + cIf*bIv) * rdI;
    const float me = (ME_AT(k) + cEf*bEv) * ldE;
    const float vpo = (k & 1) ? bfw_hi(vpw[k>>1]) : bfw_lo(vpw[k>>1]);
    const float vlo = (k & 1) ? bfw_hi(vlw[k>>1]) : bfw_lo(vlw[k>>1]);
    const float ho  = (k & 1) ? bfw_hi(hwv[k>>1]) : bfw_lo(hwv[k>>1]);
    const float vpn = silu_f(mi + vpo);
    const float vln = silu_f(me + vlo);
    hnew[k] = ho + vpn + vln;
  }

  if (b0 == b15){
    #pragma unroll
    for (int k = 0; k < 8; ++k){
      hnew[k] += __shfl_xor(hnew[k], 16, 64);
      hnew[k] += __shfl_xor(hnew[k], 32, 64);
    }
    __syncthreads();                 // mi/me reads done; safe to overwrite as pf (f32)
    if (quad == 0){
      f4v s0 = {hnew[0], hnew[1], hnew[2], hnew[3]};
      f4v s1 = {hnew[4], hnew[5], hnew[6], hnew[7]};
      *(f4v*)&pf[w][j8] = s0;
      *(f4v*)&pf[w][j8+4] = s1;
    }
    __syncthreads();
    if (tid < 128){
      const float s = pf[0][tid] + pf[1][tid] + pf[2][tid] + pf[3][tid];
      atomicAdd(&gp[(size_t)b0*H + tid], s);
    }
  } else {
    #pragma unroll
    for (int k = 0; k < 8; ++k)
      atomicAdd(&gp[(size_t)bn*H + j8 + k], hnew[k]);
  }
}

// ---------------- FC head ----------------
__global__ void k_fc(const float* __restrict__ g, const float* __restrict__ fcW,
                     const float* __restrict__ fcb, const float* __restrict__ gamma,
                     const float* __restrict__ beta, const float* __restrict__ outW,
                     const float* __restrict__ outb, float* __restrict__ out){
  __shared__ float row[H];
  __shared__ float red[H];
  const int gi = blockIdx.x;
  const int j = threadIdx.x;
  row[j] = g[(size_t)gi*H + j];
  __syncthreads();
  const float bn_scale = rsqrtf(1.0f + 1e-5f);
  for (int l = 0; l < 3; ++l){
    const float* W = fcW + (size_t)l*H*H;
    float acc = fcb[l*H + j];
    #pragma unroll 8
    for (int k = 0; k < H; ++k) acc += row[k] * W[k*H + j];
    acc = (acc > 0.f) ? acc : 0.01f*acc;             // leaky_relu
    acc = acc * bn_scale * gamma[l*H + j] + beta[l*H + j];
    __syncthreads();
    row[j] = acc;
    __syncthreads();
  }
  red[j] = row[j] * outW[j];
  __syncthreads();
  for (int o = 64; o > 0; o >>= 1){
    if (j < o) red[j] += red[j + o];
    __syncthreads();
  }
  if (j == 0) out[gi] = red[0] + outb[0];
}

extern "C" void kernel_launch(void* const* d_in, const int* in_sizes, int n_in,
                              void* d_out, int out_size, void* d_ws, size_t ws_size,
                              hipStream_t stream)
{
  const float* x    = (const float*)d_in[0];
  const int*   eii  = (const int*)  d_in[1];
  const int*   eie  = (const int*)  d_in[2];
  const float* pos  = (const float*)d_in[3];
  const float* ea   = (const float*)d_in[4];
  const int*   batch= (const int*)  d_in[5];
  const float* lnW  = (const float*)d_in[6];
  const float* lnb  = (const float*)d_in[7];
  const float* WIa  = (const float*)d_in[8];
  const float* bIa  = (const float*)d_in[9];
  const float* WEa  = (const float*)d_in[10];
  const float* bEa  = (const float*)d_in[11];
  const float* fcW  = (const float*)d_in[12];
  const float* fcb  = (const float*)d_in[13];
  const float* gam  = (const float*)d_in[14];
  const float* bet  = (const float*)d_in[15];
  const float* outW = (const float*)d_in[16];
  const float* outb = (const float*)d_in[17];
  float* out = (float*)d_out;

  const int* src_i = eii;  const int* dst_i = eii + EIN;
  const int* src_e = eie;  const int* dst_e = eie + EEX;

  const size_t NH = (size_t)NN * H;
  u16* hA = (u16*)d_ws;                    // NH
  u16* hB = hA + NH;
  u16* vp = hB + NH;
  u16* vl = vp + NH;
  u8* hA8 = (u8*)(vl + NH);                // NH bytes
  u8* hB8 = hA8 + NH;
  float* gp = (float*)(hB8 + NH);          // NG*H
  int* cnt_i = (int*)(gp + (size_t)NG*H);  // NN
  int* cnt_e = cnt_i + NN;
  int* ovfhdr = cnt_e + NN;                // 4 ints (count in [0])
  int4* ovfList = (int4*)(ovfhdr + 4);     // OVFCAP entries (16B-aligned)
  unsigned* bktI = (unsigned*)(ovfList + OVFCAP);  // NN*CAPI u32
  unsigned* bktE = bktI + (size_t)NN*CAPI;         // NN*CAPE u32
  u16* WfI = (u16*)(bktE + (size_t)NN*CAPE); // NL*H*H bf16
  u16* WfE = WfI + (size_t)NL*H*H;

  const size_t need = (size_t)((char*)(WfE + (size_t)NL*H*H) - (char*)d_ws);
  if (ws_size < need) return;

  // memset: gp + cnt + ovfhdr + ovfList + buckets (contiguous).  Zeroing the
  // buckets makes global pad slots exact (src=0, w=0) so the direct-read gather
  // needs no masking.
  const size_t z_bytes = (size_t)((char*)(bktE + (size_t)NN*CAPE) - (char*)gp);
  hipMemsetAsync(gp, 0, z_bytes, stream);

  const int NE_ALL = EIN + EEX;
  const int NBF = (NE_ALL + 256*EPT - 1)/(256*EPT);   // 1172 fill blocks
  k_prep<<<2*NL + NN/TML + NBF, 256, 0, stream>>>(x, lnW, lnb, hA, hA8, WIa, WEa, WfI, WfE,
                                                  src_i, dst_i, ea, src_e, dst_e, pos,
                                                  cnt_i, cnt_e, bktI, bktE, ovfhdr, ovfList);

  // L0: hA->hB ; L1: hB->hA ; L2: hA->hB ; L3: reads hB, pools into gp
  k_layer0<<<NTILES, 256, 0, stream>>>(hA, hA8, hB, hB8, vp, vl,
      cnt_i, cnt_e, bktI, bktE, ovfhdr, ovfList,
      WfI + 0*(size_t)H*H, bIa + 0*H, WfE + 0*(size_t)H*H, bEa + 0*H);
  k_layer<<<NTILES, 256, 0, stream>>>(hB, hB8, hA, hA8, vp, vl,
      cnt_i, cnt_e, bktI, bktE, ovfhdr, ovfList,
      WfI + 1*(size_t)H*H, bIa + 1*H, WfE + 1*(size_t)H*H, bEa + 1*H);
  k_layer<<<NTILES, 256, 0, stream>>>(hA, hA8, hB, hB8, vp, vl,
      cnt_i, cnt_e, bktI, bktE, ovfhdr, ovfList,
      WfI + 2*(size_t)H*H, bIa + 2*H, WfE + 2*(size_t)H*H, bEa + 2*H);
  k_layer3<<<NTILES, 256, 0, stream>>>(hB, hB8, vp, vl,
      cnt_i, cnt_e, bktI, bktE, ovfhdr, ovfList,
      WfI + 3*(size_t)H*H, bIa + 3*H, WfE + 3*(size_t)H*H, bEa + 3*H,
      batch, gp);

  k_fc<<<NG, H, 0, stream>>>(gp, fcW, fcb, gam, bet, outW, outb, out);
}

// Round 12
// 434.411 us; speedup vs baseline: 1.1046x; 1.1046x over previous
//
#include <hip/hip_runtime.h>
#include <math.h>

#define NN 100000
#define EIN 800000
#define EEX 400000
#define ND 35
#define H 128
#define NG 256
#define NL 4
#define TM 16          // nodes per tile (MFMA M)
#define TML 16         // nodes per block in lin_node
#define NTILES 6250    // NN/TM
#define CAPI 32        // bucket capacity intra (deg ~ Poisson(8))
#define CAPE 16        // bucket capacity inter (deg ~ Poisson(4))
#define OVFCAP 16384   // overflow list capacity
#define EPT 4          // edges per thread in fill (ILP x TLP balance)

typedef unsigned short u16;
typedef unsigned char u8;
typedef short s8v __attribute__((ext_vector_type(8)));   // 8 bf16 (4 VGPRs)
typedef float f4v __attribute__((ext_vector_type(4)));   // 4 fp32 acc
typedef float f2v __attribute__((ext_vector_type(2)));

__device__ __forceinline__ float silu_f(float x){ return x / (1.0f + __expf(-x)); }
__device__ __forceinline__ float bf2f(u16 v){ return __uint_as_float(((unsigned)v) << 16); }
__device__ __forceinline__ float bfw_lo(unsigned u){ return __uint_as_float(u << 16); }
__device__ __forceinline__ float bfw_hi(unsigned u){ return __uint_as_float(u & 0xffff0000u); }
__device__ __forceinline__ u16 f2bf(float f){
  unsigned u = __float_as_uint(f);
  u += 0x7FFFu + ((u >> 16) & 1u);   // RNE
  return (u16)(u >> 16);
}
__device__ __forceinline__ u8 f2fp8(float f){
  int p = __builtin_amdgcn_cvt_pk_fp8_f32(f, f, 0, false);   // OCP e4m3 on gfx950
  return (u8)(p & 0xff);
}
// pack two f32 -> one dword of two bf16 (RNE), same layout as manual f2bf pair
__device__ __forceinline__ unsigned pk_bf16(float lo, float hi){
  unsigned r;
  asm("v_cvt_pk_bf16_f32 %0, %1, %2" : "=v"(r) : "v"(lo), "v"(hi));
  return r;
}
// pack (src:17, bf16(w):15) -> 4B.  w > 0 so its sign bit is 0 and bf16 fits 15 bits.
__device__ __forceinline__ unsigned pack_ew(int s, float w){
  return ((unsigned)s << 15) | (unsigned)f2bf(w);
}

// ---------------- merged prep: wfrag (blocks 0..7) + MFMA lin_node + batched bucket fill ----------------
__global__ __launch_bounds__(256) void k_prep(const float* __restrict__ x,
                                              const float* __restrict__ lnW,
                                              const float* __restrict__ lnb,
                                              u16* __restrict__ h,
                                              u8* __restrict__ h8,
                                              const float* __restrict__ WI,
                                              const float* __restrict__ WE,
                                              u16* __restrict__ WfI,
                                              u16* __restrict__ WfE,
                                              const int* __restrict__ src_i,
                                              const int* __restrict__ dst_i,
                                              const float* __restrict__ ea,
                                              const int* __restrict__ src_e,
                                              const int* __restrict__ dst_e,
                                              const float* __restrict__ pos,
                                              int* __restrict__ cnt_i,
                                              int* __restrict__ cnt_e,
                                              unsigned* __restrict__ bktI,
                                              unsigned* __restrict__ bktE,
                                              int* __restrict__ ovfhdr,
                                              int4* __restrict__ ovfList){
  const int NBW = 2*NL;          // 8 weight-swizzle blocks
  const int NBL = NN/TML;        // 6250 lin_node blocks
  if (blockIdx.x < NBW){
    const int lm = blockIdx.x;
    const int l = lm >> 1;
    const float* src = (lm & 1) ? (WE + (size_t)l*H*H) : (WI + (size_t)l*H*H);
    u16* dst = ((lm & 1) ? WfE : WfI) + (size_t)l*H*H;
    for (int idx = threadIdx.x; idx < H*H; idx += 256){
      const int r = idx & 7, lane = (idx>>3)&63, kc = (idx>>9)&3, jt = idx>>11;
      const int k = kc*32 + (lane>>4)*8 + r;
      const int j = jt*16 + (lane&15);
      dst[idx] = f2bf(src[k*H + j]);
    }
    return;
  }
  if (blockIdx.x < NBW + NBL){
    // ---- MFMA lin_node: h = silu(x @ lnW + lnb), 16 nodes/block ----
    __shared__ u16 xs[TM][72];   // row pad 72: 2-way bank alias only (free, m136)
    const int n0 = (blockIdx.x - NBW) * TML;
    const int tid = threadIdx.x;
    for (int i = tid; i < TM*64; i += 256){
      const int m = i >> 6, k = i & 63;
      xs[m][k] = (k < ND) ? f2bf(x[(size_t)(n0+m)*ND + k]) : (u16)0;
    }
    __syncthreads();
    const int lane = tid & 63;
    const int wv   = tid >> 6;
    const int col  = lane & 15;
    const int quad = lane >> 4;
    const int jta = 2*wv, jtb = 2*wv + 1;
    const int ja = jta*16 + col, jb = jtb*16 + col;

    f4v accA = {0.f,0.f,0.f,0.f}, accB = {0.f,0.f,0.f,0.f};
    #pragma unroll
    for (int kc = 0; kc < 2; ++kc){
      const s8v a = *(const s8v*)&xs[col][kc*32 + quad*8];
      s8v bA, bB;
      #pragma unroll
      for (int r = 0; r < 8; ++r){
        const int k = kc*32 + quad*8 + r;
        bA[r] = (k < ND) ? (short)f2bf(lnW[k*H + ja]) : (short)0;
        bB[r] = (k < ND) ? (short)f2bf(lnW[k*H + jb]) : (short)0;
      }
      accA = __builtin_amdgcn_mfma_f32_16x16x32_bf16(a, bA, accA, 0, 0, 0);
      accB = __builtin_amdgcn_mfma_f32_16x16x32_bf16(a, bB, accB, 0, 0, 0);
    }
    const float bja = lnb[ja], bjb = lnb[jb];
    #pragma unroll
    for (int r = 0; r < 4; ++r){
      const int n = n0 + quad*4 + r;           // C/D: col=lane&15, row=quad*4+reg (m89)
      const float ha = silu_f(accA[r] + bja);
      const float hb = silu_f(accB[r] + bjb);
      h[(size_t)n*H + ja] = f2bf(ha);
      h[(size_t)n*H + jb] = f2bf(hb);
      h8[(size_t)n*H + ja] = f2fp8(ha);
      h8[(size_t)n*H + jb] = f2fp8(hb);
    }
    return;
  }
  // ---- batched bucket fill: EPT edges/thread, EPT atomics in flight ----
  const int NE_ALL_ = EIN + EEX;
  const int base = (blockIdx.x - NBW - NBL)*(256*EPT) + (int)threadIdx.x;
  int eV[EPT], sV[EPT], dV[EPT];
  #pragma unroll
  for (int k = 0; k < EPT; ++k){
    const int e = base + k*256;
    eV[k] = e;
    int s = 0, d = 0;
    if (e < EIN){ s = src_i[e]; d = dst_i[e]; }
    else if (e < NE_ALL_){ s = src_e[e-EIN]; d = dst_e[e-EIN]; }
    sV[k] = s; dV[k] = d;
  }
  float wV[EPT];
  #pragma unroll
  for (int k = 0; k < EPT; ++k){
    const int e = eV[k];
    float w = 0.f;
    if (e < EIN) w = ea[e];
    else if (e < NE_ALL_){
      const int s = sV[k], d = dV[k];
      const float dx = pos[3*s+0] - pos[3*d+0];
      const float dy = pos[3*s+1] - pos[3*d+1];
      const float dz = pos[3*s+2] - pos[3*d+2];
      w = __expf(-(dx*dx + dy*dy + dz*dz));
    }
    wV[k] = w;
  }
  #pragma unroll
  for (int k = 0; k < EPT; ++k){
    const int e = eV[k];
    if (e < EIN){
      const int slot = atomicAdd(&cnt_i[dV[k]], 1);
      if (slot < CAPI) bktI[((size_t)dV[k] << 5) + slot] = pack_ew(sV[k], wV[k]);
      else {
        const int oi = atomicAdd(ovfhdr, 1);
        if (oi < OVFCAP) ovfList[oi] = make_int4(dV[k], sV[k], __float_as_int(wV[k]), 0);
      }
    } else if (e < NE_ALL_){
      const int slot = atomicAdd(&cnt_e[dV[k]], 1);
      if (slot < CAPE) bktE[((size_t)dV[k] << 4) + slot] = pack_ew(sV[k], wV[k]);
      else {
        const int oi = atomicAdd(ovfhdr, 1);
        if (oi < OVFCAP) ovfList[oi] = make_int4(dV[k], sV[k], __float_as_int(wV[k]), 1);
      }
    }
  }
}

// accumulate one fp8x8 row-chunk (two dwords) scaled by vv into 4 f2v accumulators
#define ACCONE(qx, qy, vv, A0, A1, A2, A3) {                                          \
    const f2v x01 = __builtin_amdgcn_cvt_pk_f32_fp8((int)(qx), false);                \
    const f2v x23 = __builtin_amdgcn_cvt_pk_f32_fp8((int)(qx), true);                 \
    const f2v x45 = __builtin_amdgcn_cvt_pk_f32_fp8((int)(qy), false);                \
    const f2v x67 = __builtin_amdgcn_cvt_pk_f32_fp8((int)(qy), true);                 \
    A0 += x01 * (vv); A1 += x23 * (vv); A2 += x45 * (vv); A3 += x67 * (vv); }

// ---------------- shared memory: time-shared between phases ----------------
#define GATHER_SHARED_DECL                                                            \
  __shared__ __align__(16) char smem_[16896];                                         \
  u16 (*aggIs)[136] = (u16(*)[136])(smem_);                                           \
  u16 (*aggEs)[136] = (u16(*)[136])(smem_ + 4352);                                    \
  unsigned (*edI)[CAPI] = (unsigned(*)[CAPI])(smem_ + 8704);   /* 16x32x4 = 2048 */   \
  unsigned (*edE)[CAPE] = (unsigned(*)[CAPE])(smem_ + 10752);  /* 16x16x4 = 1024 */   \
  float (*mif)[132] = (float(*)[132])(smem_);                                         \
  float (*mef)[132] = (float(*)[132])(smem_ + 8448);

// per-thread identity + degrees (live through the whole kernel)
#define GATHER_DECLS                                                                  \
  const int slot = tid >> 4;                                                          \
  const int l16  = tid & 15;                                                          \
  const int j8 = l16 * 8;                                                             \
  const int n = n0 + slot;                                                            \
  const int cIv = cntI[n];                                                            \
  const int cEv = cntE[n];

// 8-deep intra + 4-deep inter batches (pad to 8/4 with (src=0,w=0) -> exact 0.0
// contribution); packed 4B entries read via uint4 from LDS.
#define GATHER_LDS_BODY                                                               \
  {                                                                                   \
    const int uI = cIv < CAPI ? cIv : CAPI;                                           \
    const int uE = cEv < CAPE ? cEv : CAPE;                                           \
    const int pIv = (uI + 7) & ~7;                                                    \
    const int pEv = (uE + 3) & ~3;                                                    \
    {                                                                                 \
      const size_t bI_ = ((size_t)n << 5);                                            \
      for (int t = l16; t < pIv; t += 16)                                             \
        edI[slot][t] = (t < uI) ? bktI[bI_ + t] : 0u;                                 \
      const size_t bE_ = ((size_t)n << 4);                                            \
      if (l16 < pEv)                                                                  \
        edE[slot][l16] = (l16 < uE) ? bktE[bE_ + l16] : 0u;                           \
    }                                                                                 \
    __syncthreads();                                                                  \
    f2v aI0={0.f,0.f}, aI1={0.f,0.f}, aI2={0.f,0.f}, aI3={0.f,0.f};                   \
    f2v aE0={0.f,0.f}, aE1={0.f,0.f}, aE2={0.f,0.f}, aE3={0.f,0.f};                   \
    {                                                                                 \
      const int nbI_ = pIv >> 3, nbE_ = pEv >> 2;                                     \
      const int nb = nbI_ > nbE_ ? nbI_ : nbE_;                                       \
      int tIi = 0, tEi = 0;                                                           \
      for (int b = 0; b < nb; ++b){                                                   \
        const bool doI = b < nbI_;                                                    \
        const bool doE = b < nbE_;                                                    \
        unsigned eIw[8], eEw[4]; uint2 qI[8], qE[4];                                  \
        if (doI){                                                                     \
          *(uint4*)&eIw[0] = *(const uint4*)&edI[slot][tIi+0];                        \
          *(uint4*)&eIw[4] = *(const uint4*)&edI[slot][tIi+4];                        \
          _Pragma("unroll")                                                           \
          for (int k = 0; k < 8; ++k){                                                \
            const unsigned off = ((eIw[k] >> 15) << 7) | (unsigned)j8;                \
            qI[k] = *(const uint2*)(hin8 + off);                                      \
          }                                                                           \
        }                                                                             \
        if (doE){                                                                     \
          *(uint4*)&eEw[0] = *(const uint4*)&edE[slot][tEi+0];                        \
          _Pragma("unroll")                                                           \
          for (int k = 0; k < 4; ++k){                                                \
            const unsigned off = ((eEw[k] >> 15) << 7) | (unsigned)j8;                \
            qE[k] = *(const uint2*)(hin8 + off);                                      \
          }                                                                           \
        }                                                                             \
        if (doI){                                                                     \
          _Pragma("unroll")                                                           \
          for (int k = 0; k < 8; ++k){                                                \
            const float v = __uint_as_float((eIw[k] & 0x7fffu) << 16);                \
            ACCONE(qI[k].x, qI[k].y, v, aI0, aI1, aI2, aI3)                           \
          }                                                                           \
          tIi += 8;                                                                   \
        }                                                                             \
        if (doE){                                                                     \
          _Pragma("unroll")                                                           \
          for (int k = 0; k < 4; ++k){                                                \
            const float v = __uint_as_float((eEw[k] & 0x7fffu) << 16);                \
            ACCONE(qE[k].x, qE[k].y, v, aE0, aE1, aE2, aE3)                           \
          }                                                                           \
          tEi += 4;                                                                   \
        }                                                                             \
      }                                                                               \
    }                                                                                 \
    const int nov = ovfhdr[0];                                                        \
    if (__builtin_expect(nov > 0, 0)){                                                \
      const int novc = nov < OVFCAP ? nov : OVFCAP;                                   \
      for (int o = 0; o < novc; ++o){                                                 \
        const int4 E = ovfList[o];                                                    \
        if (E.x == n){                                                                \
          const unsigned off = ((unsigned)E.y << 7) | (unsigned)j8;                   \
          const uint2 q = *(const uint2*)(hin8 + off);                                \
          const float v = __int_as_float(E.z);                                        \
          if (E.w == 0){ ACCONE(q.x, q.y, v, aI0, aI1, aI2, aI3) }                    \
          else         { ACCONE(q.x, q.y, v, aE0, aE1, aE2, aE3) }                    \
        }                                                                             \
      }                                                                               \
    }                                                                                 \
    *(uint4*)&aggIs[slot][j8] = make_uint4(pk_bf16(aI0.x, aI0.y), pk_bf16(aI1.x, aI1.y), \
                                           pk_bf16(aI2.x, aI2.y), pk_bf16(aI3.x, aI3.y)); \
    *(uint4*)&aggEs[slot][j8] = make_uint4(pk_bf16(aE0.x, aE0.y), pk_bf16(aE1.x, aE1.y), \
                                           pk_bf16(aE2.x, aE2.y), pk_bf16(aE3.x, aE3.y)); \
  }

#define MFMA_BODY                                                                     \
  f4v accIA = {0.f,0.f,0.f,0.f}, accIB = {0.f,0.f,0.f,0.f};                           \
  f4v accEA = {0.f,0.f,0.f,0.f}, accEB = {0.f,0.f,0.f,0.f};                           \
  _Pragma("unroll")                                                                   \
  for (int kc = 0; kc < 4; ++kc){                                                     \
    const int koff = kc*32 + quad*8;                                                  \
    const s8v aI = *(const s8v*)&aggIs[col][koff];                                    \
    const s8v aE = *(const s8v*)&aggEs[col][koff];                                    \
    const s8v bIA = *(const s8v*)(WfI + (((jta*4 + kc)*64 + lane) << 3));             \
    const s8v bIB = *(const s8v*)(WfI + (((jtb*4 + kc)*64 + lane) << 3));             \
    const s8v bEA = *(const s8v*)(WfE + (((jta*4 + kc)*64 + lane) << 3));             \
    const s8v bEB = *(const s8v*)(WfE + (((jtb*4 + kc)*64 + lane) << 3));             \
    accIA = __builtin_amdgcn_mfma_f32_16x16x32_bf16(aI, bIA, accIA, 0, 0, 0);         \
    accIB = __builtin_amdgcn_mfma_f32_16x16x32_bf16(aI, bIB, accIB, 0, 0, 0);         \
    accEA = __builtin_amdgcn_mfma_f32_16x16x32_bf16(aE, bEA, accEA, 0, 0, 0);         \
    accEB = __builtin_amdgcn_mfma_f32_16x16x32_bf16(aE, bEB, accEB, 0, 0, 0);         \
  }

// transpose acc (C-layout, scattered) -> LDS [node][col] f32; stride 132.
#define ACC2LDS                                                                       \
  __syncthreads();                                                                    \
  _Pragma("unroll")                                                                   \
  for (int r = 0; r < 4; ++r){                                                        \
    mif[quad*4+r][jta*16+col] = accIA[r];                                             \
    mif[quad*4+r][jtb*16+col] = accIB[r];                                             \
    mef[quad*4+r][jta*16+col] = accEA[r];                                             \
    mef[quad*4+r][jtb*16+col] = accEB[r];                                             \
  }                                                                                   \
  __syncthreads();

#define EPI_COMMON                                                                    \
  const float cIf = (float)cIv;                                                       \
  const float cEf = (float)cEv;                                                       \
  const float rdI = 1.0f / (cIf + 1.0f);                                              \
  const float ldE = __logf(cEf + 1.0f);                                               \
  const f4v miA = *(const f4v*)&mif[slot][j8];                                        \
  const f4v miB = *(const f4v*)&mif[slot][j8+4];                                      \
  const f4v meA = *(const f4v*)&mef[slot][j8];                                        \
  const f4v meB = *(const f4v*)&mef[slot][j8+4];                                      \
  const f4v bIa_ = *(const f4v*)(bI + j8);                                            \
  const f4v bIb_ = *(const f4v*)(bI + j8 + 4);                                        \
  const f4v bEa_ = *(const f4v*)(bE + j8);                                            \
  const f4v bEb_ = *(const f4v*)(bE + j8 + 4);                                        \
  const unsigned idx8 = (unsigned)n*H + (unsigned)j8;

#define STORE_STATE8                                                                  \
  uint4 vps, vls, hs;                                                                 \
  vps.x = pk_bf16(vpn[0],vpn[1]); vps.y = pk_bf16(vpn[2],vpn[3]);                     \
  vps.z = pk_bf16(vpn[4],vpn[5]); vps.w = pk_bf16(vpn[6],vpn[7]);                     \
  vls.x = pk_bf16(vln[0],vln[1]); vls.y = pk_bf16(vln[2],vln[3]);                     \
  vls.z = pk_bf16(vln[4],vln[5]); vls.w = pk_bf16(vln[6],vln[7]);                     \
  hs.x = pk_bf16(hnew[0],hnew[1]); hs.y = pk_bf16(hnew[2],hnew[3]);                   \
  hs.z = pk_bf16(hnew[4],hnew[5]); hs.w = pk_bf16(hnew[6],hnew[7]);                   \
  *(uint4*)(vp + idx8) = vps;                                                         \
  *(uint4*)(vl + idx8) = vls;                                                         \
  *(uint4*)(hout + idx8) = hs;                                                        \
  int d0_ = __builtin_amdgcn_cvt_pk_fp8_f32(hnew[0], hnew[1], 0, false);              \
  d0_ = __builtin_amdgcn_cvt_pk_fp8_f32(hnew[2], hnew[3], d0_, true);                 \
  int d1_ = __builtin_amdgcn_cvt_pk_fp8_f32(hnew[4], hnew[5], 0, false);              \
  d1_ = __builtin_amdgcn_cvt_pk_fp8_f32(hnew[6], hnew[7], d1_, true);                 \
  uint2 h8s; h8s.x = (unsigned)d0_; h8s.y = (unsigned)d1_;                            \
  *(uint2*)(hout8 + idx8) = h8s;

// ---------------- layers 1..2: read state, write hout + fp8 mirror ----------------
__global__ __launch_bounds__(256, 4) void k_layer(
    const u16* __restrict__ hin, const u8* __restrict__ hin8,
    u16* __restrict__ hout, u8* __restrict__ hout8,
    u16* __restrict__ vp, u16* __restrict__ vl,
    const int* __restrict__ cntI, const int* __restrict__ cntE,
    const unsigned* __restrict__ bktI, const unsigned* __restrict__ bktE,
    const int* __restrict__ ovfhdr, const int4* __restrict__ ovfList,
    const u16* __restrict__ WfI, const float* __restrict__ bI,
    const u16* __restrict__ WfE, const float* __restrict__ bE)
{
  GATHER_SHARED_DECL
  const int n0 = blockIdx.x * TM;
  const int tid = threadIdx.x;
  GATHER_DECLS
  GATHER_LDS_BODY
  __syncthreads();

  const int lane = tid & 63;
  const int w    = tid >> 6;
  const int jta = 2*w, jtb = 2*w + 1;
  const int col  = lane & 15;
  const int quad = lane >> 4;
  MFMA_BODY
  ACC2LDS

  EPI_COMMON
  const uint4 vpq = *(const uint4*)(vp + idx8);
  const uint4 vlq = *(const uint4*)(vl + idx8);
  const uint4 hq  = *(const uint4*)(hin + idx8);
  const unsigned vpw[4] = {vpq.x, vpq.y, vpq.z, vpq.w};
  const unsigned vlw[4] = {vlq.x, vlq.y, vlq.z, vlq.w};
  const unsigned hwv[4] = {hq.x, hq.y, hq.z, hq.w};
  float vpn[8], vln[8], hnew[8];
  #pragma unroll
  for (int k = 0; k < 8; ++k){
    const float miv = (k < 4) ? miA[k] : miB[k-4];
    const float mev = (k < 4) ? meA[k] : meB[k-4];
    const float bIv = (k < 4) ? bIa_[k] : bIb_[k-4];
    const float bEv = (k < 4) ? bEa_[k] : bEb_[k-4];
    const float mi = (miv + cIf*bIv) * rdI;
    const float me = (mev + cEf*bEv) * ldE;
    const float vpo = (k & 1) ? bfw_hi(vpw[k>>1]) : bfw_lo(vpw[k>>1]);
    const float vlo = (k & 1) ? bfw_hi(vlw[k>>1]) : bfw_lo(vlw[k>>1]);
    const float ho  = (k & 1) ? bfw_hi(hwv[k>>1]) : bfw_lo(hwv[k>>1]);
    vpn[k] = silu_f(mi + vpo);
    vln[k] = silu_f(me + vlo);
    hnew[k] = ho + vpn[k] + vln[k];
  }
  STORE_STATE8
}

// ---------------- layer 0: vp/vl start at zero (no reads) ----------------
__global__ __launch_bounds__(256, 4) void k_layer0(
    const u16* __restrict__ hin, const u8* __restrict__ hin8,
    u16* __restrict__ hout, u8* __restrict__ hout8,
    u16* __restrict__ vp, u16* __restrict__ vl,
    const int* __restrict__ cntI, const int* __restrict__ cntE,
    const unsigned* __restrict__ bktI, const unsigned* __restrict__ bktE,
    const int* __restrict__ ovfhdr, const int4* __restrict__ ovfList,
    const u16* __restrict__ WfI, const float* __restrict__ bI,
    const u16* __restrict__ WfE, const float* __restrict__ bE)
{
  GATHER_SHARED_DECL
  const int n0 = blockIdx.x * TM;
  const int tid = threadIdx.x;
  GATHER_DECLS
  GATHER_LDS_BODY
  __syncthreads();

  const int lane = tid & 63;
  const int w    = tid >> 6;
  const int jta = 2*w, jtb = 2*w + 1;
  const int col  = lane & 15;
  const int quad = lane >> 4;
  MFMA_BODY
  ACC2LDS

  EPI_COMMON
  const uint4 hq = *(const uint4*)(hin + idx8);
  const unsigned hwv[4] = {hq.x, hq.y, hq.z, hq.w};
  float vpn[8], vln[8], hnew[8];
  #pragma unroll
  for (int k = 0; k < 8; ++k){
    const float miv = (k < 4) ? miA[k] : miB[k-4];
    const float mev = (k < 4) ? meA[k] : meB[k-4];
    const float bIv = (k < 4) ? bIa_[k] : bIb_[k-4];
    const float bEv = (k < 4) ? bEa_[k] : bEb_[k-4];
    const float mi = (miv + cIf*bIv) * rdI;
    const float me = (mev + cEf*bEv) * ldE;
    const float ho = (k & 1) ? bfw_hi(hwv[k>>1]) : bfw_lo(hwv[k>>1]);
    vpn[k] = silu_f(mi);
    vln[k] = silu_f(me);
    hnew[k] = ho + vpn[k] + vln[k];
  }
  STORE_STATE8
}

// ---------------- layer 3: NO state stores; pool fused from registers ----------------
__global__ __launch_bounds__(256, 4) void k_layer3(
    const u16* __restrict__ hin, const u8* __restrict__ hin8,
    u16* __restrict__ vp, u16* __restrict__ vl,
    const int* __restrict__ cntI, const int* __restrict__ cntE,
    const unsigned* __restrict__ bktI, const unsigned* __restrict__ bktE,
    const int* __restrict__ ovfhdr, const int4* __restrict__ ovfList,
    const u16* __restrict__ WfI, const float* __restrict__ bI,
    const u16* __restrict__ WfE, const float* __restrict__ bE,
    const int* __restrict__ batch, float* __restrict__ gp)
{
  GATHER_SHARED_DECL
  const int n0 = blockIdx.x * TM;
  const int tid = threadIdx.x;
  GATHER_DECLS
  GATHER_LDS_BODY
  __syncthreads();

  const int lane = tid & 63;
  const int w    = tid >> 6;
  const int jta = 2*w, jtb = 2*w + 1;
  const int col  = lane & 15;
  const int quad = lane >> 4;
  MFMA_BODY
  ACC2LDS

  EPI_COMMON
  const uint4 vpq = *(const uint4*)(vp + idx8);
  const uint4 vlq = *(const uint4*)(vl + idx8);
  const uint4 hq  = *(const uint4*)(hin + idx8);
  const unsigned vpw[4] = {vpq.x, vpq.y, vpq.z, vpq.w};
  const unsigned vlw[4] = {vlq.x, vlq.y, vlq.z, vlq.w};
  const unsigned hwv[4] = {hq.x, hq.y, hq.z, hq.w};
  float hnew[8];
  #pragma unroll
  for (int k = 0; k < 8; ++k){
    const float miv = (k < 4) ? miA[k] : miB[k-4];
    const float mev = (k < 4) ? meA[k] : meB[k-4];
    const float bIv = (k < 4) ? bIa_[k] : bIb_[k-4];
    const float bEv = (k < 4) ? bEa_[k] : bEb_[k-4];
    const float mi = (miv + cIf*bIv) * rdI;
    const float me = (mev + cEf*bEv) * ldE;
    const float vpo = (k & 1) ? bfw_hi(vpw[k>>1]) : bfw_lo(vpw[k>>1]);
    const float vlo = (k & 1) ? bfw_hi(vlw[k>>1]) : bfw_lo(vlw[k>>1]);
    const float ho  = (k & 1) ? bfw_hi(hwv[k>>1]) : bfw_lo(hwv[k>>1]);
    const float vpn = silu_f(mi + vpo);
    const float vln = silu_f(me + vlo);
    hnew[k] = ho + vpn + vln;
  }

  const int b0 = batch[n0];
  const int b15 = batch[n0 + TM - 1];
  if (b0 == b15){
    #pragma unroll
    for (int k = 0; k < 8; ++k){
      hnew[k] += __shfl_xor(hnew[k], 16, 64);
      hnew[k] += __shfl_xor(hnew[k], 32, 64);
    }
    __syncthreads();                 // mi/me reads done; safe to overwrite mif
    if (quad == 0){
      f4v s0 = {hnew[0], hnew[1], hnew[2], hnew[3]};
      f4v s1 = {hnew[4], hnew[5], hnew[6], hnew[7]};
      *(f4v*)&mif[w][j8] = s0;
      *(f4v*)&mif[w][j8+4] = s1;
    }
    __syncthreads();
    if (tid < 128){
      const float s = mif[0][tid] + mif[1][tid] + mif[2][tid] + mif[3][tid];
      atomicAdd(&gp[(size_t)b0*H + tid], s);
    }
  } else {
    const int bn = batch[n];
    #pragma unroll
    for (int k = 0; k < 8; ++k)
      atomicAdd(&gp[(size_t)bn*H + j8 + k], hnew[k]);
  }
}

// ---------------- FC head ----------------
__global__ void k_fc(const float* __restrict__ g, const float* __restrict__ fcW,
                     const float* __restrict__ fcb, const float* __restrict__ gamma,
                     const float* __restrict__ beta, const float* __restrict__ outW,
                     const float* __restrict__ outb, float* __restrict__ out){
  __shared__ float row[H];
  __shared__ float red[H];
  const int gi = blockIdx.x;
  const int j = threadIdx.x;
  row[j] = g[(size_t)gi*H + j];
  __syncthreads();
  const float bn_scale = rsqrtf(1.0f + 1e-5f);
  for (int l = 0; l < 3; ++l){
    const float* W = fcW + (size_t)l*H*H;
    float acc = fcb[l*H + j];
    #pragma unroll 8
    for (int k = 0; k < H; ++k) acc += row[k] * W[k*H + j];
    acc = (acc > 0.f) ? acc : 0.01f*acc;             // leaky_relu
    acc = acc * bn_scale * gamma[l*H + j] + beta[l*H + j];
    __syncthreads();
    row[j] = acc;
    __syncthreads();
  }
  red[j] = row[j] * outW[j];
  __syncthreads();
  for (int o = 64; o > 0; o >>= 1){
    if (j < o) red[j] += red[j + o];
    __syncthreads();
  }
  if (j == 0) out[gi] = red[0] + outb[0];
}

extern "C" void kernel_launch(void* const* d_in, const int* in_sizes, int n_in,
                              void* d_out, int out_size, void* d_ws, size_t ws_size,
                              hipStream_t stream)
{
  const float* x    = (const float*)d_in[0];
  const int*   eii  = (const int*)  d_in[1];
  const int*   eie  = (const int*)  d_in[2];
  const float* pos  = (const float*)d_in[3];
  const float* ea   = (const float*)d_in[4];
  const int*   batch= (const int*)  d_in[5];
  const float* lnW  = (const float*)d_in[6];
  const float* lnb  = (const float*)d_in[7];
  const float* WIa  = (const float*)d_in[8];
  const float* bIa  = (const float*)d_in[9];
  const float* WEa  = (const float*)d_in[10];
  const float* bEa  = (const float*)d_in[11];
  const float* fcW  = (const float*)d_in[12];
  const float* fcb  = (const float*)d_in[13];
  const float* gam  = (const float*)d_in[14];
  const float* bet  = (const float*)d_in[15];
  const float* outW = (const float*)d_in[16];
  const float* outb = (const float*)d_in[17];
  float* out = (float*)d_out;

  const int* src_i = eii;  const int* dst_i = eii + EIN;
  const int* src_e = eie;  const int* dst_e = eie + EEX;

  const size_t NH = (size_t)NN * H;
  u16* hA = (u16*)d_ws;                    // NH
  u16* hB = hA + NH;
  u16* vp = hB + NH;
  u16* vl = vp + NH;
  u8* hA8 = (u8*)(vl + NH);                // NH bytes
  u8* hB8 = hA8 + NH;
  float* gp = (float*)(hB8 + NH);          // NG*H
  int* cnt_i = (int*)(gp + (size_t)NG*H);  // NN
  int* cnt_e = cnt_i + NN;
  int* ovfhdr = cnt_e + NN;                // 4 ints (count in [0])
  int4* ovfList = (int4*)(ovfhdr + 4);     // OVFCAP entries (16B-aligned)
  unsigned* bktI = (unsigned*)(ovfList + OVFCAP);  // NN*CAPI u32
  unsigned* bktE = bktI + (size_t)NN*CAPI;         // NN*CAPE u32
  u16* WfI = (u16*)(bktE + (size_t)NN*CAPE); // NL*H*H bf16
  u16* WfE = WfI + (size_t)NL*H*H;

  const size_t need = (size_t)((char*)(WfE + (size_t)NL*H*H) - (char*)d_ws);
  if (ws_size < need) return;

  // memset: gp + cnt_i + cnt_e + ovfhdr (contiguous)
  hipMemsetAsync(gp, 0, ((size_t)NG*H + 2*(size_t)NN + 4)*sizeof(int), stream);

  const int NE_ALL = EIN + EEX;
  const int NBF = (NE_ALL + 256*EPT - 1)/(256*EPT);   // 1172 fill blocks
  k_prep<<<2*NL + NN/TML + NBF, 256, 0, stream>>>(x, lnW, lnb, hA, hA8, WIa, WEa, WfI, WfE,
                                                  src_i, dst_i, ea, src_e, dst_e, pos,
                                                  cnt_i, cnt_e, bktI, bktE, ovfhdr, ovfList);

  // L0: hA->hB ; L1: hB->hA ; L2: hA->hB ; L3: reads hB, pools into gp
  k_layer0<<<NTILES, 256, 0, stream>>>(hA, hA8, hB, hB8, vp, vl,
      cnt_i, cnt_e, bktI, bktE, ovfhdr, ovfList,
      WfI + 0*(size_t)H*H, bIa + 0*H, WfE + 0*(size_t)H*H, bEa + 0*H);
  k_layer<<<NTILES, 256, 0, stream>>>(hB, hB8, hA, hA8, vp, vl,
      cnt_i, cnt_e, bktI, bktE, ovfhdr, ovfList,
      WfI + 1*(size_t)H*H, bIa + 1*H, WfE + 1*(size_t)H*H, bEa + 1*H);
  k_layer<<<NTILES, 256, 0, stream>>>(hA, hA8, hB, hB8, vp, vl,
      cnt_i, cnt_e, bktI, bktE, ovfhdr, ovfList,
      WfI + 2*(size_t)H*H, bIa + 2*H, WfE + 2*(size_t)H*H, bEa + 2*H);
  k_layer3<<<NTILES, 256, 0, stream>>>(hB, hB8, vp, vl,
      cnt_i, cnt_e, bktI, bktE, ovfhdr, ovfList,
      WfI + 3*(size_t)H*H, bIa + 3*H, WfE + 3*(size_t)H*H, bEa + 3*H,
      batch, gp);

  k_fc<<<NG, H, 0, stream>>>(gp, fcW, fcb, gam, bet, outW, outb, out);
}